// Round 1
// baseline (794.806 us; speedup 1.0000x reference)
//
#include <hip/hip_runtime.h>
#include <math.h>

#define NB 32
#define IMGS 640          // NB*20 images per backbone
#define HW 224
#define CHW (3*224*224)
#define P1 37             // pooled dim after stage1
#define P1SQ (37*37)

// ---------------------------------------------------------------------------
// Stage 1: fused conv1(3->3, 3x3, stride2, VALID) + maxpool 3x3 s3 + relu.
// One thread per (img, ph, pw) pooled position; computes all 3 out channels.
// grid: (ceil(640*1369/256), 2 backbones), block 256.
// Input window per thread: 3ch x 7rows x cols [6pw, 6pw+7] (8B-aligned float2s).
// ---------------------------------------------------------------------------
__global__ __launch_bounds__(256) void stage1(
    const float* __restrict__ nodes, const float* __restrict__ depths,
    const float* __restrict__ c1w, const float* __restrict__ c1b,
    const float* __restrict__ dc1w, const float* __restrict__ dc1b,
    float* __restrict__ s1)   // [2][640][3][37][37]
{
    const int bb = blockIdx.y;
    const int g = blockIdx.x * 256 + threadIdx.x;
    if (g >= IMGS * P1SQ) return;
    const int img = g / P1SQ;
    const int p   = g - img * P1SQ;
    const int ph  = p / P1;
    const int pw  = p - ph * P1;

    const float* __restrict__ x    = (bb ? depths : nodes) + (size_t)img * CHW;
    const float* __restrict__ w    = bb ? dc1w : c1w;   // [3][3][3][3]
    const float* __restrict__ bias = bb ? dc1b : c1b;

    float acc[3][9];
    #pragma unroll
    for (int oc = 0; oc < 3; ++oc)
        #pragma unroll
        for (int q = 0; q < 9; ++q) acc[oc][q] = 0.f;

    const int row0 = 6 * ph;   // max 222
    const int col0 = 6 * pw;   // max 216; reads cols up to 223

    #pragma unroll
    for (int i = 0; i < 3; ++i) {
        #pragma unroll
        for (int r = 0; r < 7; ++r) {
            const float2* rp = (const float2*)(x + (size_t)i*(HW*HW) + (size_t)(row0 + r)*HW + col0);
            const float2 v0 = rp[0], v1 = rp[1], v2 = rp[2], v3 = rp[3];
            const float row[8] = {v0.x, v0.y, v1.x, v1.y, v2.x, v2.y, v3.x, v3.y};
            #pragma unroll
            for (int dh = 0; dh < 3; ++dh) {
                const int kh = r - 2*dh;
                if (kh < 0 || kh > 2) continue;   // compile-time resolved
                #pragma unroll
                for (int oc = 0; oc < 3; ++oc) {
                    #pragma unroll
                    for (int dw = 0; dw < 3; ++dw) {
                        #pragma unroll
                        for (int kw = 0; kw < 3; ++kw) {
                            acc[oc][dh*3+dw] += row[2*dw+kw] * w[((oc*3+i)*3+kh)*3+kw];
                        }
                    }
                }
            }
        }
    }

    #pragma unroll
    for (int oc = 0; oc < 3; ++oc) {
        float m = acc[oc][0];
        #pragma unroll
        for (int q = 1; q < 9; ++q) m = fmaxf(m, acc[oc][q]);
        m = fmaxf(m + bias[oc], 0.f);   // bias const over pool window; relu after pool
        s1[(((size_t)bb*IMGS + img)*3 + oc)*P1SQ + p] = m;
    }
}

// ---------------------------------------------------------------------------
// Stage 2: fused conv2(3->1, 3x3, stride2) + maxpool 3x3 s3 + relu + [36x6]
// linear. One block per (backbone, image). grid 1280, block 128.
// ---------------------------------------------------------------------------
__global__ __launch_bounds__(128) void stage2(
    const float* __restrict__ s1,
    const float* __restrict__ c2w, const float* __restrict__ c2b,
    const float* __restrict__ dc2w, const float* __restrict__ dc2b,
    const float* __restrict__ lw, const float* __restrict__ lb,
    const float* __restrict__ dlw, const float* __restrict__ dlb,
    float* __restrict__ feats)  // [2][640][6]
{
    const int bb  = blockIdx.x / IMGS;
    const int img = blockIdx.x - bb*IMGS;
    const float* __restrict__ w   = bb ? dc2w : c2w;   // [3][3][3]
    const float* __restrict__ lwp = bb ? dlw : lw;     // [36][6]
    const float* __restrict__ lbp = bb ? dlb : lb;
    const float b2 = (bb ? dc2b : c2b)[0];

    __shared__ float t1[3*P1SQ];  // 4107 floats
    __shared__ float v[36];

    const float* __restrict__ src = s1 + ((size_t)bb*IMGS + img)*3*P1SQ;
    for (int e = threadIdx.x; e < 3*P1SQ; e += 128) t1[e] = src[e];
    __syncthreads();

    const int t = threadIdx.x;
    if (t < 36) {
        const int py = t / 6, px = t - py*6;
        float m = -INFINITY;
        #pragma unroll
        for (int dh = 0; dh < 3; ++dh) {
            #pragma unroll
            for (int dw = 0; dw < 3; ++dw) {
                const int h = 3*py + dh, wv = 3*px + dw;   // conv coords 0..17
                float a = b2;
                #pragma unroll
                for (int i = 0; i < 3; ++i)
                    #pragma unroll
                    for (int kh = 0; kh < 3; ++kh)
                        #pragma unroll
                        for (int kw = 0; kw < 3; ++kw)
                            a += t1[i*P1SQ + (2*h+kh)*P1 + (2*wv+kw)] * w[(i*3+kh)*3+kw];
                m = fmaxf(m, a);
            }
        }
        v[t] = fmaxf(m, 0.f);
    }
    __syncthreads();
    if (t < 6) {
        float a = lbp[t];
        #pragma unroll
        for (int k = 0; k < 36; ++k) a += v[k] * lwp[k*6+t];
        feats[((size_t)bb*IMGS + img)*6 + t] = a;
    }
}

// ---------------------------------------------------------------------------
// Stage 3: message passing + concat + MLP(360->180->60->6). One block/sample.
// grid 32, block 192.
// ---------------------------------------------------------------------------
__global__ __launch_bounds__(192) void stage3(
    const float* __restrict__ pos, const float* __restrict__ att,
    const float* __restrict__ fmw, const float* __restrict__ fmb,
    const float* __restrict__ lmw, const float* __restrict__ lmb,
    const float* __restrict__ o1w, const float* __restrict__ o1b,
    const float* __restrict__ o2w, const float* __restrict__ o2b,
    const float* __restrict__ o3w, const float* __restrict__ o3b,
    const float* __restrict__ feats,   // [2][640][6]
    float* __restrict__ out)           // [32][6]
{
    const int n = blockIdx.x;
    const int t = threadIdx.x;
    __shared__ float feat[360];
    __shared__ float h1[180];
    __shared__ float h2[60];

    // copy nf (half=0) / df (half=1) into feat slots [.. +0..5] / [.. +6..11]
    for (int u = t; u < 240; u += 192) {
        const int half = u / 120;
        const int idx  = u - half*120;
        const int fn   = idx / 6;        // f*4+node, 0..19
        const int j    = idx - fn*6;
        feat[fn*18 + half*6 + j] = feats[(size_t)half*(IMGS*6) + (n*20 + fn)*6 + j];
    }
    // message passing -> feat slots [.. +12..17]
    if (t < 120) {
        const int f    = t / 24;
        const int r    = t - f*24;
        const int node = r / 6;
        const int d    = r - node*6;
        float m = 0.f;
        #pragma unroll
        for (int mm = 0; mm < 4; ++mm) {          // sum over sender mm
            float pmd = fmb[d];
            #pragma unroll
            for (int e = 0; e < 6; ++e)
                pmd += pos[(((size_t)n*5+f)*4+mm)*6+e] * fmw[e*6+d];
            m += att[(((size_t)n*5+f)*4+mm)*4+node] * pmd;
        }
        if (f >= 1) {                              // temporal message from f-1
            float pv = lmb[d];
            #pragma unroll
            for (int e = 0; e < 6; ++e)
                pv += pos[(((size_t)n*5+(f-1))*4+node)*6+e] * lmw[e*6+d];
            m += pv;
        }
        feat[(f*4+node)*18 + 12 + d] = m;
    }
    __syncthreads();
    if (t < 180) {
        float a = o1b[t];
        for (int k = 0; k < 360; ++k) a += feat[k] * o1w[(size_t)k*180 + t];
        h1[t] = fmaxf(a, 0.f);
    }
    __syncthreads();
    if (t < 60) {
        float a = o2b[t];
        for (int k = 0; k < 180; ++k) a += h1[k] * o2w[k*60 + t];
        h2[t] = fmaxf(a, 0.f);
    }
    __syncthreads();
    if (t < 6) {
        float a = o3b[t];
        #pragma unroll
        for (int k = 0; k < 60; ++k) a += h2[k] * o3w[k*6 + t];
        out[n*6 + t] = a;
    }
}

extern "C" void kernel_launch(void* const* d_in, const int* in_sizes, int n_in,
                              void* d_out, int out_size, void* d_ws, size_t ws_size,
                              hipStream_t stream)
{
    const float* nodes  = (const float*)d_in[0];
    const float* pos    = (const float*)d_in[1];
    const float* att    = (const float*)d_in[2];
    const float* depths = (const float*)d_in[3];
    const float* c1w  = (const float*)d_in[4];
    const float* c1b  = (const float*)d_in[5];
    const float* c2w  = (const float*)d_in[6];
    const float* c2b  = (const float*)d_in[7];
    const float* lw   = (const float*)d_in[8];
    const float* lb   = (const float*)d_in[9];
    const float* dc1w = (const float*)d_in[10];
    const float* dc1b = (const float*)d_in[11];
    const float* dc2w = (const float*)d_in[12];
    const float* dc2b = (const float*)d_in[13];
    const float* dlw  = (const float*)d_in[14];
    const float* dlb  = (const float*)d_in[15];
    const float* fmw  = (const float*)d_in[16];
    const float* fmb  = (const float*)d_in[17];
    const float* lmw  = (const float*)d_in[18];
    const float* lmb  = (const float*)d_in[19];
    const float* o1w  = (const float*)d_in[20];
    const float* o1b  = (const float*)d_in[21];
    const float* o2w  = (const float*)d_in[22];
    const float* o2b  = (const float*)d_in[23];
    const float* o3w  = (const float*)d_in[24];
    const float* o3b  = (const float*)d_in[25];

    float* s1    = (float*)d_ws;                     // 2*640*3*1369 floats = 21.0 MB
    float* feats = s1 + (size_t)2*IMGS*3*P1SQ;       // 2*640*6 floats

    dim3 g1((IMGS*P1SQ + 255)/256, 2);
    stage1<<<g1, 256, 0, stream>>>(nodes, depths, c1w, c1b, dc1w, dc1b, s1);
    stage2<<<dim3(2*IMGS), 128, 0, stream>>>(s1, c2w, c2b, dc2w, dc2b,
                                             lw, lb, dlw, dlb, feats);
    stage3<<<dim3(NB), 192, 0, stream>>>(pos, att, fmw, fmb, lmw, lmb,
                                         o1w, o1b, o2w, o2b, o3w, o3b,
                                         feats, (float*)d_out);
}